// Round 2
// baseline (508.522 us; speedup 1.0000x reference)
//
#include <hip/hip_runtime.h>

#define B_ 16
#define H_ 384
#define W_ 384
#define C_ 32   // floats per pixel; 8 float4 per pixel

#define RPB 8                    // rows per block (loop)
#define CPB 32                   // cols per block (256 threads = 32 cols x 8 float4)
#define XB  (W_ / CPB)           // 12 col-blocks per row
#define YT  (H_ / RPB)           // 48 row-tiles per image
#define BPI (XB * YT)            // 576 blocks per image
#define NBLK (BPI * B_)          // 9216 total blocks
#define NXCD 8
#define CPX (NBLK / NXCD)        // 1152 blocks per XCD (exact)

// native vector type for __builtin_nontemporal_store (HIP_vector_type rejected)
typedef float f4_native __attribute__((ext_vector_type(4)));

// Each block: 32 cols x 8 rows of one image. XCD-swizzled so each XCD owns
// two whole images walked row-major (vertical tap reuse stays XCD-L2-local;
// 7/8 of it is intra-block and L1-local).
__global__ __launch_bounds__(256) void st_bilinear_kernel(
    const float* __restrict__ images,
    const float* __restrict__ theta,
    float* __restrict__ out)
{
    // ---- bijective XCD swizzle: hw round-robins blockIdx.x % 8 over XCDs ----
    const int lb  = (blockIdx.x & (NXCD - 1)) * CPX + (blockIdx.x >> 3);
    const int b   = lb / BPI;
    const int rem = lb - b * BPI;
    const int yt  = rem / XB;
    const int xb  = rem - yt * XB;

    const int t  = threadIdx.x;
    const int c4 = t & 7;                 // which float4 of the 32 channels
    const int w  = xb * CPB + (t >> 3);   // column
    const int h0 = yt * RPB;              // first row of this block's tile

    // ---- adjusted theta in FP64 (uniform per block; hoisted out of row loop) ----
    const float* th = theta + b * 6;
    const double t0 = (double)th[0], t1 = (double)th[1], t2 = (double)th[2];
    const double t3 = (double)th[3], t4 = (double)th[4], t5 = (double)th[5];
    const double inv_det = 1.0 / (t0 * t4 - t1 * t3);
    const double a00 =  t4 * inv_det;   // mul[0,0]
    const double a01 = -t1 * inv_det;   // mul[0,1]
    const double a10 = -t3 * inv_det;   // mul[1,0]
    const double a11 =  t0 * inv_det;   // mul[1,1]
    const double x_center = (0.5 - t2) * a00;
    const double y_center = (0.5 - t5) * a11;
    const double c0 = 2.0 * y_center - 1.0;  // grid channel 0 offset (-> x)
    const double c1 = 2.0 * x_center - 1.0;  // grid channel 1 offset (-> y)

    // ---- normalized x coord, replicating np.linspace(-1,1,N) in f64 ----
    const double step = 2.0 / 383.0;
    const double xs = (w == W_ - 1) ? 1.0 : (double)w * step - 1.0;

    const float4* img4 = (const float4*)images;
    const int pix_stride = C_ / 4;          // 8 float4 per pixel
    const int row_stride = W_ * pix_stride; // per image row
    const int base_b = b * (H_ * row_stride);
    f4_native* out4 = (f4_native*)out;
    int out_idx = base_b + (h0 * W_ + w) * pix_stride + c4;

    #pragma unroll 2
    for (int r = 0; r < RPB; ++r) {
        const int h = h0 + r;
        const double ys = (h == H_ - 1) ? 1.0 : (double)h * step - 1.0;

        const double gx = (a00 * xs + a01 * ys) + c0;
        const double gy = (a10 * xs + a11 * ys) + c1;

        const double x = (gx + 1.0) * ((double)W_ * 0.5);
        const double y = (gy + 1.0) * ((double)H_ * 0.5);

        // ---- bilinear indices/weights in f64 (identical to passing kernel) ----
        const double xf = floor(x);
        const double yf = floor(y);
        int x0 = (int)xf, y0 = (int)yf;
        int x1 = x0 + 1,  y1 = y0 + 1;
        x0 = min(max(x0, 0), W_ - 1);
        x1 = min(max(x1, 0), W_ - 1);
        y0 = min(max(y0, 0), H_ - 1);
        y1 = min(max(y1, 0), H_ - 1);
        const double x0f = (double)x0, x1f = (double)x1;
        const double y0f = (double)y0, y1f = (double)y1;
        const float wa = (float)((x1f - x) * (y1f - y));
        const float wb = (float)((x1f - x) * (y - y0f));
        const float wc = (float)((x - x0f) * (y1f - y));
        const float wd = (float)((x - x0f) * (y - y0f));

        // ---- gather 4 neighbors (each pixel contiguous 128B; this lane's float4) ----
        const int r0 = base_b + y0 * row_stride;
        const int r1 = base_b + y1 * row_stride;
        const int cx0 = x0 * pix_stride + c4;
        const int cx1 = x1 * pix_stride + c4;

        const float4 ga = img4[r0 + cx0];
        const float4 gb = img4[r1 + cx0];
        const float4 gc = img4[r0 + cx1];
        const float4 gd = img4[r1 + cx1];

        f4_native o;
        o.x = wa * ga.x + wb * gb.x + wc * gc.x + wd * gd.x;
        o.y = wa * ga.y + wb * gb.y + wc * gc.y + wd * gd.y;
        o.z = wa * ga.z + wb * gb.z + wc * gc.z + wd * gd.z;
        o.w = wa * ga.w + wb * gb.w + wc * gc.w + wd * gd.w;

        // write-once output: nontemporal so the store stream doesn't evict
        // the input stripe from L2
        __builtin_nontemporal_store(o, &out4[out_idx]);
        out_idx += row_stride;
    }
}

extern "C" void kernel_launch(void* const* d_in, const int* in_sizes, int n_in,
                              void* d_out, int out_size, void* d_ws, size_t ws_size,
                              hipStream_t stream) {
    const float* images = (const float*)d_in[0];
    const float* theta  = (const float*)d_in[1];
    float* out = (float*)d_out;

    dim3 grid(NBLK, 1, 1);   // 9216 blocks, 1-D for the XCD swizzle
    dim3 block(256, 1, 1);
    st_bilinear_kernel<<<grid, block, 0, stream>>>(images, theta, out);
}